// Round 12
// baseline (342.600 us; speedup 1.0000x reference)
//
#include <hip/hip_runtime.h>
#include <hip/hip_bf16.h>

typedef __attribute__((ext_vector_type(4))) float f32x4;
typedef __attribute__((ext_vector_type(8))) short short8;
typedef __attribute__((ext_vector_type(4))) short short4v;

#define EDIM 512
#define WELEMS 262144  // 512*512

static __device__ __forceinline__ short f2bf(float f) {
  union { float f; unsigned u; } v; v.f = f;
  unsigned r = v.u + 0x7fffu + ((v.u >> 16) & 1u);  // RNE
  return (short)(r >> 16);
}
static __device__ __forceinline__ float bf2f(short s) {
  union { float f; unsigned u; } v; v.u = ((unsigned)(unsigned short)s) << 16;
  return v.f;
}

// async global -> LDS, 16B per lane; lds base wave-uniform + lane*16 linear.
static __device__ __forceinline__ void gload_lds16(const short* g, short* l) {
  __builtin_amdgcn_global_load_lds(
      (const __attribute__((address_space(1))) unsigned int*)g,
      (__attribute__((address_space(3))) unsigned int*)(unsigned int)(unsigned long long)l,
      16, 0, 0);
}

// ---- merged prep + state convert, one dispatch ----
// blocks [0,256): Wv->bf16 | [256,264): tvec = Wk^T bq | [264,520): H = Wk^T Wq
// blocks [prep_blocks, ...): states fp32->bf16 (pure streaming)
__global__ __launch_bounds__(256) void prep_convert(
    const float* __restrict__ s1, const float* __restrict__ s2,
    const float* __restrict__ Wq, const float* __restrict__ bq,
    const float* __restrict__ Wk, const float* __restrict__ Wv,
    short* __restrict__ Wvb, float* __restrict__ tvec, short* __restrict__ Hb,
    short* __restrict__ o1, short* __restrict__ o2, int prep_blocks) {
  __shared__ float sh[2][64][33];
  const int b = blockIdx.x;
  const int tid = threadIdx.x;
  if (b < prep_blocks) {
    if (b < 256) {
      int i = (b * 256 + tid) * 4;
      f32x4 v = *(const f32x4*)(Wv + i);
      short4v vs;
#pragma unroll
      for (int j = 0; j < 4; ++j) vs[j] = f2bf(v[j]);
      *(short4v*)(Wvb + i) = vs;
    } else if (b < 264) {
      float* red = &sh[0][0][0];  // [4][64]
      const int fl = tid & 63;
      const int part = tid >> 6;
      const int f = (b - 256) * 64 + fl;
      float s = 0.f;
      const int n0 = part * 128;
#pragma unroll 8
      for (int n = n0; n < n0 + 128; ++n) s += Wk[(size_t)n * EDIM + f] * bq[n];
      red[part * 64 + fl] = s;
      __syncthreads();
      if (part == 0)
        tvec[f] = ((red[fl] + red[64 + fl]) + (red[128 + fl] + red[192 + fl]));
    } else {
      const int hb = b - 264;
      const int bf = (hb >> 4) * 32;
      const int be = (hb & 15) * 32;
      const int fh = (tid & 15) * 2;
      const int eh = (tid >> 4) * 2;
      float a00 = 0, a01 = 0, a10 = 0, a11 = 0;
      for (int nc = 0; nc < 8; ++nc) {
        __syncthreads();
#pragma unroll
        for (int p = 0; p < 8; ++p) {
          const int idx = p * 256 + tid;  // 2048 = 64n x 32f
          const int n = idx >> 5, f = idx & 31;
          sh[0][n][f] = Wk[(size_t)(nc * 64 + n) * EDIM + bf + f];
          sh[1][n][f] = Wq[(size_t)(nc * 64 + n) * EDIM + be + f];
        }
        __syncthreads();
#pragma unroll 4
        for (int n = 0; n < 64; ++n) {
          const float k0 = sh[0][n][fh], k1 = sh[0][n][fh + 1];
          const float q0 = sh[1][n][eh], q1 = sh[1][n][eh + 1];
          a00 += k0 * q0; a01 += k0 * q1; a10 += k1 * q0; a11 += k1 * q1;
        }
      }
      Hb[(size_t)(bf + fh) * EDIM + be + eh] = f2bf(a00);
      Hb[(size_t)(bf + fh) * EDIM + be + eh + 1] = f2bf(a01);
      Hb[(size_t)(bf + fh + 1) * EDIM + be + eh] = f2bf(a10);
      Hb[(size_t)(bf + fh + 1) * EDIM + be + eh + 1] = f2bf(a11);
    }
  } else {
    const int cb = b - prep_blocks;
    const int wv = tid >> 6, lane = tid & 63;
    const size_t r = (size_t)cb * 4 + wv;
    const int off = lane * 8;
#pragma unroll
    for (int st = 0; st < 2; ++st) {
      const float* src = st ? s2 : s1;
      f32x4 a0 = *(const f32x4*)(src + r * EDIM + off);
      f32x4 a1 = *(const f32x4*)(src + r * EDIM + off + 4);
      short8 rb;
#pragma unroll
      for (int j = 0; j < 4; ++j) { rb[j] = f2bf(a0[j]); rb[j + 4] = f2bf(a1[j]); }
      *(short8*)((st ? o2 : o1) + r * EDIM + off) = rb;
    }
  }
}

// ------- T GEMM (r7 structure, 5 blocks/CU): T_d = X_d @ H^T, bf16 out -------
// grid = mblocks*8: zn = 8 combos (2 dirs x 4 nb), XCD decode.
__global__ __launch_bounds__(256, 5) void proj_t(
    const short* __restrict__ S1b, const short* __restrict__ S2b,
    const short* __restrict__ Hb,
    short* __restrict__ TV, size_t McE, int mblocks) {
  __shared__ short Al[128 * 64];
  __shared__ short Bl[128 * 64];

  int mb, zn;
  {
    const int L = blockIdx.x;
    if ((mblocks & 7) == 0) {
      const int mpx = mblocks >> 3;
      const int xcd = L & 7;
      const int slot = L >> 3;
      mb = xcd * mpx + slot / 8;
      zn = slot % 8;
    } else { mb = L / 8; zn = L % 8; }
  }
  const int z = zn >> 2;   // dir
  const int nb = zn & 3;

  const short* __restrict__ X = z ? S2b : S1b;
  short* __restrict__ O = TV + (size_t)z * McE;

  const int m0 = mb * 128;
  const int n0 = nb * 128;
  const int tid = threadIdx.x;
  const int lane = tid & 63;
  const int wv = tid >> 6;
  const int wr = wv >> 1, wc = wv & 1;
  const int col = lane & 15;
  const int kg = lane >> 4;

  f32x4 acc[4][4] = {};

  for (int ks = 0; ks < EDIM / 64; ++ks) {
    const int k0 = ks * 64;
    __syncthreads();
#pragma unroll
    for (int j = 0; j < 4; ++j) {
      const int g = (j * 4 + wv) * 64 + lane;
      const int row = g >> 3;
      const int sc = (g & 7) ^ (row & 7);
      gload_lds16(X + (size_t)(m0 + row) * EDIM + k0 + sc * 8, Al + (j * 4 + wv) * 512);
      gload_lds16(Hb + (size_t)(n0 + row) * EDIM + k0 + sc * 8, Bl + (j * 4 + wv) * 512);
    }
    __syncthreads();
#pragma unroll
    for (int kk = 0; kk < 2; ++kk) {
      short8 af[4], bf8[4];
#pragma unroll
      for (int i = 0; i < 4; ++i) {
        const int ra = wr * 64 + i * 16 + col;
        const int rb = wc * 64 + i * 16 + col;
        af[i]  = *(const short8*)(Al + ra * 64 + ((((kk << 2) + kg) ^ (ra & 7)) << 3));
        bf8[i] = *(const short8*)(Bl + rb * 64 + ((((kk << 2) + kg) ^ (rb & 7)) << 3));
      }
#pragma unroll
      for (int mi = 0; mi < 4; ++mi)
#pragma unroll
        for (int nj = 0; nj < 4; ++nj)
          acc[mi][nj] = __builtin_amdgcn_mfma_f32_16x16x32_bf16(af[mi], bf8[nj], acc[mi][nj], 0, 0, 0);
    }
  }

#pragma unroll
  for (int mi = 0; mi < 4; ++mi) {
#pragma unroll
    for (int j = 0; j < 4; ++j) {
      const size_t r = m0 + wr * 64 + mi * 16 + kg * 4 + j;
#pragma unroll
      for (int nj = 0; nj < 4; ++nj) {
        const int e = n0 + wc * 64 + nj * 16 + col;
        O[r * EDIM + e] = f2bf(acc[mi][nj][j]);
      }
    }
  }
}

// ------- block attention -> Y = P @ X (bf16) -------
// S = T@X^T + w[k], w[k] = X[k]·tvec computed in-loop from the K fragments;
// kg-reduce via shfl_xor(16|32). V eliminated (out = (P@X)@Wv^T + bv).
__global__ __launch_bounds__(256) void attn_y(
    const short* __restrict__ TV, const short* __restrict__ S1b, const short* __restrict__ S2b,
    const float* __restrict__ tvec, size_t McE) {
  __shared__ float plds[4][16][16];
  const int dir = blockIdx.y;
  const short* __restrict__ Q = TV + (size_t)dir * McE;     // T1 : T2
  const short* __restrict__ KV = dir ? S1b : S2b;
  short* __restrict__ Y = (short*)TV + (size_t)(2 + dir) * McE;

  const int lane = threadIdx.x & 63;
  const int wv = threadIdx.x >> 6;
  const size_t r0 = ((size_t)blockIdx.x * 4 + wv) * 16;
  const int col = lane & 15;
  const int kg = lane >> 4;

  const short* Qp = Q + (r0 + col) * EDIM + kg * 8;
  const short* Kp = KV + (r0 + col) * EDIM + kg * 8;
  f32x4 s = {};
  float wp = 0.f;
#pragma unroll
  for (int ks = 0; ks < 16; ++ks) {
    short8 a = *(const short8*)(Qp + ks * 32);
    short8 b = *(const short8*)(Kp + ks * 32);
    const f32x4 t0 = *(const f32x4*)(tvec + ks * 32 + kg * 8);
    const f32x4 t1 = *(const f32x4*)(tvec + ks * 32 + kg * 8 + 4);
#pragma unroll
    for (int i = 0; i < 4; ++i)
      wp += bf2f(b[i]) * t0[i] + bf2f(b[i + 4]) * t1[i];
    s = __builtin_amdgcn_mfma_f32_16x16x32_bf16(a, b, s, 0, 0, 0);
  }
  wp += __shfl_xor(wp, 16);
  wp += __shfl_xor(wp, 32);

  const float scale = 0.04419417382415922f;  // 1/sqrt(512)
  float p[4];
#pragma unroll
  for (int j = 0; j < 4; ++j) p[j] = (s[j] + wp) * scale;
#pragma unroll
  for (int j = 0; j < 4; ++j) {
    float m = p[j];
#pragma unroll
    for (int d = 1; d < 16; d <<= 1) m = fmaxf(m, __shfl_xor(m, d));
    float e = __expf(p[j] - m);
    float ssum = e;
#pragma unroll
    for (int d = 1; d < 16; d <<= 1) ssum += __shfl_xor(ssum, d);
    p[j] = e / ssum;
  }
#pragma unroll
  for (int j = 0; j < 4; ++j) plds[wv][kg * 4 + j][col] = p[j];
  __syncthreads();

  const int e0 = lane * 8;
  short8 v8[16];
#pragma unroll
  for (int k = 0; k < 16; ++k) v8[k] = *(const short8*)(KV + (r0 + k) * EDIM + e0);
#pragma unroll
  for (int q = 0; q < 16; ++q) {
    float acc[8] = {0, 0, 0, 0, 0, 0, 0, 0};
#pragma unroll
    for (int k = 0; k < 16; ++k) {
      const float pv = plds[wv][q][k];
#pragma unroll
      for (int i = 0; i < 8; ++i) acc[i] += pv * bf2f(v8[k][i]);
    }
    short8 y;
#pragma unroll
    for (int i = 0; i < 8; ++i) y[i] = f2bf(acc[i]);
    *(short8*)(Y + (r0 + q) * EDIM + e0) = y;
  }
}

// ------- out GEMM (r7 structure, 5 blocks/CU): out_d = Y_d @ Wv^T + bv, fp32 out ---
__global__ __launch_bounds__(256, 5) void out_gemm(
    const short* __restrict__ TV, const short* __restrict__ Wvb,
    const float* __restrict__ bv,
    float* __restrict__ out1, float* __restrict__ out2, size_t McE, int mblocks) {
  __shared__ short Al[128 * 64];
  __shared__ short Bl[128 * 64];

  int mb, zn;
  {
    const int L = blockIdx.x;
    if ((mblocks & 7) == 0) {
      const int mpx = mblocks >> 3;
      const int xcd = L & 7;
      const int slot = L >> 3;
      mb = xcd * mpx + slot / 8;
      zn = slot % 8;
    } else { mb = L / 8; zn = L % 8; }
  }
  const int z = zn >> 2;   // dir
  const int nb = zn & 3;

  const short* __restrict__ A = TV + (size_t)(2 + z) * McE;  // Y1 : Y2
  float* __restrict__ O = z ? out2 : out1;

  const int m0 = mb * 128;
  const int n0 = nb * 128;
  const int tid = threadIdx.x;
  const int lane = tid & 63;
  const int wv = tid >> 6;
  const int wr = wv >> 1, wc = wv & 1;
  const int col = lane & 15;
  const int kg = lane >> 4;

  f32x4 acc[4][4] = {};

  for (int ks = 0; ks < EDIM / 64; ++ks) {
    const int k0 = ks * 64;
    __syncthreads();
#pragma unroll
    for (int j = 0; j < 4; ++j) {
      const int g = (j * 4 + wv) * 64 + lane;
      const int row = g >> 3;
      const int sc = (g & 7) ^ (row & 7);
      gload_lds16(A + (size_t)(m0 + row) * EDIM + k0 + sc * 8, Al + (j * 4 + wv) * 512);
      gload_lds16(Wvb + (size_t)(n0 + row) * EDIM + k0 + sc * 8, Bl + (j * 4 + wv) * 512);
    }
    __syncthreads();
#pragma unroll
    for (int kk = 0; kk < 2; ++kk) {
      short8 af[4], bf8[4];
#pragma unroll
      for (int i = 0; i < 4; ++i) {
        const int ra = wr * 64 + i * 16 + col;
        const int rb = wc * 64 + i * 16 + col;
        af[i]  = *(const short8*)(Al + ra * 64 + ((((kk << 2) + kg) ^ (ra & 7)) << 3));
        bf8[i] = *(const short8*)(Bl + rb * 64 + ((((kk << 2) + kg) ^ (rb & 7)) << 3));
      }
#pragma unroll
      for (int mi = 0; mi < 4; ++mi)
#pragma unroll
        for (int nj = 0; nj < 4; ++nj)
          acc[mi][nj] = __builtin_amdgcn_mfma_f32_16x16x32_bf16(af[mi], bf8[nj], acc[mi][nj], 0, 0, 0);
    }
  }

#pragma unroll
  for (int mi = 0; mi < 4; ++mi) {
#pragma unroll
    for (int j = 0; j < 4; ++j) {
      const size_t r = m0 + wr * 64 + mi * 16 + kg * 4 + j;
#pragma unroll
      for (int nj = 0; nj < 4; ++nj) {
        const int e = n0 + wc * 64 + nj * 16 + col;
        O[r * EDIM + e] = acc[mi][nj][j] + bv[e];
      }
    }
  }
}

// ---------------- host ----------------
extern "C" void kernel_launch(void* const* d_in, const int* in_sizes, int n_in,
                              void* d_out, int out_size, void* d_ws, size_t ws_size,
                              hipStream_t stream) {
  const float* state1 = (const float*)d_in[0];
  const float* state2 = (const float*)d_in[1];
  const float* Wq = (const float*)d_in[2];
  const float* bq = (const float*)d_in[3];
  const float* Wk = (const float*)d_in[4];
  // d_in[5] = bk: softmax-invariant -> unused
  const float* Wv = (const float*)d_in[6];
  const float* bv = (const float*)d_in[7];

  const size_t Mtot = (size_t)8 * 4096;
  float* out1 = (float*)d_out;
  float* out2 = out1 + Mtot * EDIM;

  // ws layout: Wvb | Hb | tvec | per-chunk {S1b, S2b, T1,T2,Y1,Y2}
  short* Wvb = (short*)d_ws;
  short* Hb = Wvb + WELEMS;
  float* tvec = (float*)(Hb + WELEMS);
  short* base = (short*)(tvec + EDIM);

  const size_t fixed_bytes = (size_t)(2 * WELEMS) * 2 + EDIM * 4;
  size_t nch = 1;
  while (nch < 256) {
    size_t need = fixed_bytes + (size_t)6 * (Mtot / nch) * EDIM * 2;
    if (need <= ws_size) break;
    nch <<= 1;
  }
  const size_t Mc = Mtot / nch;
  const size_t McE = Mc * EDIM;
  const int mblocks = (int)(Mc / 128);
  short* S1b = base;
  short* S2b = S1b + McE;
  short* TV = S2b + McE;  // T1, T2, Y1, Y2

  for (size_t c = 0; c < nch; ++c) {
    const size_t roff = c * Mc;
    const int pb = (c == 0) ? 520 : 0;  // prep only on first chunk
    prep_convert<<<dim3((unsigned)(Mc / 4 + pb)), dim3(256), 0, stream>>>(
        state1 + roff * EDIM, state2 + roff * EDIM, Wq, bq, Wk, Wv,
        Wvb, tvec, Hb, S1b, S2b, pb);
    proj_t<<<dim3((unsigned)(mblocks * 8)), dim3(256), 0, stream>>>(
        S1b, S2b, Hb, TV, McE, mblocks);
    attn_y<<<dim3((unsigned)(Mc / 64), 2), dim3(256), 0, stream>>>(
        TV, S1b, S2b, tvec, McE);
    out_gemm<<<dim3((unsigned)(mblocks * 8)), dim3(256), 0, stream>>>(
        TV, Wvb, bv, out1 + roff * EDIM, out2 + roff * EDIM, McE, mblocks);
  }
}

// Round 13
// 185.498 us; speedup vs baseline: 1.8469x; 1.8469x over previous
//
#include <hip/hip_runtime.h>
#include <hip/hip_bf16.h>

typedef __attribute__((ext_vector_type(4))) float f32x4;
typedef __attribute__((ext_vector_type(8))) short short8;
typedef __attribute__((ext_vector_type(4))) short short4v;

#define EDIM 512
#define WELEMS 262144  // 512*512

static __device__ __forceinline__ short f2bf(float f) {
  union { float f; unsigned u; } v; v.f = f;
  unsigned r = v.u + 0x7fffu + ((v.u >> 16) & 1u);  // RNE
  return (short)(r >> 16);
}
static __device__ __forceinline__ float bf2f(short s) {
  union { float f; unsigned u; } v; v.u = ((unsigned)(unsigned short)s) << 16;
  return v.f;
}

// async global -> LDS, 16B per lane; lds base wave-uniform + lane*16 linear.
static __device__ __forceinline__ void gload_lds16(const short* g, short* l) {
  __builtin_amdgcn_global_load_lds(
      (const __attribute__((address_space(1))) unsigned int*)g,
      (__attribute__((address_space(3))) unsigned int*)(unsigned int)(unsigned long long)l,
      16, 0, 0);
}

// ---- merged prep + state convert, one dispatch ----
// blocks [0,256): Wv->bf16 | [256,264): tvec = Wk^T bq | [264,520): H = Wk^T Wq
// blocks [prep_blocks, ...): states fp32->bf16 (pure streaming)
__global__ __launch_bounds__(256) void prep_convert(
    const float* __restrict__ s1, const float* __restrict__ s2,
    const float* __restrict__ Wq, const float* __restrict__ bq,
    const float* __restrict__ Wk, const float* __restrict__ Wv,
    short* __restrict__ Wvb, float* __restrict__ tvec, short* __restrict__ Hb,
    short* __restrict__ o1, short* __restrict__ o2, int prep_blocks) {
  __shared__ float sh[2][64][33];
  const int b = blockIdx.x;
  const int tid = threadIdx.x;
  if (b < prep_blocks) {
    if (b < 256) {
      int i = (b * 256 + tid) * 4;
      f32x4 v = *(const f32x4*)(Wv + i);
      short4v vs;
#pragma unroll
      for (int j = 0; j < 4; ++j) vs[j] = f2bf(v[j]);
      *(short4v*)(Wvb + i) = vs;
    } else if (b < 264) {
      float* red = &sh[0][0][0];  // [4][64]
      const int fl = tid & 63;
      const int part = tid >> 6;
      const int f = (b - 256) * 64 + fl;
      float s = 0.f;
      const int n0 = part * 128;
#pragma unroll 8
      for (int n = n0; n < n0 + 128; ++n) s += Wk[(size_t)n * EDIM + f] * bq[n];
      red[part * 64 + fl] = s;
      __syncthreads();
      if (part == 0)
        tvec[f] = ((red[fl] + red[64 + fl]) + (red[128 + fl] + red[192 + fl]));
    } else {
      const int hb = b - 264;
      const int bf = (hb >> 4) * 32;
      const int be = (hb & 15) * 32;
      const int fh = (tid & 15) * 2;
      const int eh = (tid >> 4) * 2;
      float a00 = 0, a01 = 0, a10 = 0, a11 = 0;
      for (int nc = 0; nc < 8; ++nc) {
        __syncthreads();
#pragma unroll
        for (int p = 0; p < 8; ++p) {
          const int idx = p * 256 + tid;  // 2048 = 64n x 32f
          const int n = idx >> 5, f = idx & 31;
          sh[0][n][f] = Wk[(size_t)(nc * 64 + n) * EDIM + bf + f];
          sh[1][n][f] = Wq[(size_t)(nc * 64 + n) * EDIM + be + f];
        }
        __syncthreads();
#pragma unroll 4
        for (int n = 0; n < 64; ++n) {
          const float k0 = sh[0][n][fh], k1 = sh[0][n][fh + 1];
          const float q0 = sh[1][n][eh], q1 = sh[1][n][eh + 1];
          a00 += k0 * q0; a01 += k0 * q1; a10 += k1 * q0; a11 += k1 * q1;
        }
      }
      Hb[(size_t)(bf + fh) * EDIM + be + eh] = f2bf(a00);
      Hb[(size_t)(bf + fh) * EDIM + be + eh + 1] = f2bf(a01);
      Hb[(size_t)(bf + fh + 1) * EDIM + be + eh] = f2bf(a10);
      Hb[(size_t)(bf + fh + 1) * EDIM + be + eh + 1] = f2bf(a11);
    }
  } else {
    const int cb = b - prep_blocks;
    const int wv = tid >> 6, lane = tid & 63;
    const size_t r = (size_t)cb * 4 + wv;
    const int off = lane * 8;
#pragma unroll
    for (int st = 0; st < 2; ++st) {
      const float* src = st ? s2 : s1;
      f32x4 a0 = *(const f32x4*)(src + r * EDIM + off);
      f32x4 a1 = *(const f32x4*)(src + r * EDIM + off + 4);
      short8 rb;
#pragma unroll
      for (int j = 0; j < 4; ++j) { rb[j] = f2bf(a0[j]); rb[j + 4] = f2bf(a1[j]); }
      *(short8*)((st ? o2 : o1) + r * EDIM + off) = rb;
    }
  }
}

// ------- T GEMM (r7 structure, 4 blocks/CU): T_d = X_d @ H^T, bf16 out -------
// grid = mblocks*8: zn = 8 combos (2 dirs x 4 nb), XCD decode.
// NOTE: 4 waves/EU is the max safe bound here (unified VGPR+acc ~124 <= 128);
// 5 waves/EU (cap ~102) spills the MFMA accumulators to scratch (r12: 3x slower).
__global__ __launch_bounds__(256, 4) void proj_t(
    const short* __restrict__ S1b, const short* __restrict__ S2b,
    const short* __restrict__ Hb,
    short* __restrict__ TV, size_t McE, int mblocks) {
  __shared__ short Al[128 * 64];
  __shared__ short Bl[128 * 64];

  int mb, zn;
  {
    const int L = blockIdx.x;
    if ((mblocks & 7) == 0) {
      const int mpx = mblocks >> 3;
      const int xcd = L & 7;
      const int slot = L >> 3;
      mb = xcd * mpx + slot / 8;
      zn = slot % 8;
    } else { mb = L / 8; zn = L % 8; }
  }
  const int z = zn >> 2;   // dir
  const int nb = zn & 3;

  const short* __restrict__ X = z ? S2b : S1b;
  short* __restrict__ O = TV + (size_t)z * McE;

  const int m0 = mb * 128;
  const int n0 = nb * 128;
  const int tid = threadIdx.x;
  const int lane = tid & 63;
  const int wv = tid >> 6;
  const int wr = wv >> 1, wc = wv & 1;
  const int col = lane & 15;
  const int kg = lane >> 4;

  f32x4 acc[4][4] = {};

  for (int ks = 0; ks < EDIM / 64; ++ks) {
    const int k0 = ks * 64;
    __syncthreads();
#pragma unroll
    for (int j = 0; j < 4; ++j) {
      const int g = (j * 4 + wv) * 64 + lane;
      const int row = g >> 3;
      const int sc = (g & 7) ^ (row & 7);
      gload_lds16(X + (size_t)(m0 + row) * EDIM + k0 + sc * 8, Al + (j * 4 + wv) * 512);
      gload_lds16(Hb + (size_t)(n0 + row) * EDIM + k0 + sc * 8, Bl + (j * 4 + wv) * 512);
    }
    __syncthreads();
#pragma unroll
    for (int kk = 0; kk < 2; ++kk) {
      short8 af[4], bf8[4];
#pragma unroll
      for (int i = 0; i < 4; ++i) {
        const int ra = wr * 64 + i * 16 + col;
        const int rb = wc * 64 + i * 16 + col;
        af[i]  = *(const short8*)(Al + ra * 64 + ((((kk << 2) + kg) ^ (ra & 7)) << 3));
        bf8[i] = *(const short8*)(Bl + rb * 64 + ((((kk << 2) + kg) ^ (rb & 7)) << 3));
      }
#pragma unroll
      for (int mi = 0; mi < 4; ++mi)
#pragma unroll
        for (int nj = 0; nj < 4; ++nj)
          acc[mi][nj] = __builtin_amdgcn_mfma_f32_16x16x32_bf16(af[mi], bf8[nj], acc[mi][nj], 0, 0, 0);
    }
  }

#pragma unroll
  for (int mi = 0; mi < 4; ++mi) {
#pragma unroll
    for (int j = 0; j < 4; ++j) {
      const size_t r = m0 + wr * 64 + mi * 16 + kg * 4 + j;
#pragma unroll
      for (int nj = 0; nj < 4; ++nj) {
        const int e = n0 + wc * 64 + nj * 16 + col;
        O[r * EDIM + e] = f2bf(acc[mi][nj][j]);
      }
    }
  }
}

// ------- block attention -> Y = P @ X (bf16) -------
// S = T@X^T + w[k], w[k] = X[k]·tvec computed in-loop from the K fragments;
// kg-reduce via shfl_xor(16|32). V eliminated (out = (P@X)@Wv^T + bv).
__global__ __launch_bounds__(256) void attn_y(
    const short* __restrict__ TV, const short* __restrict__ S1b, const short* __restrict__ S2b,
    const float* __restrict__ tvec, size_t McE) {
  __shared__ float plds[4][16][16];
  const int dir = blockIdx.y;
  const short* __restrict__ Q = TV + (size_t)dir * McE;     // T1 : T2
  const short* __restrict__ KV = dir ? S1b : S2b;
  short* __restrict__ Y = (short*)TV + (size_t)(2 + dir) * McE;

  const int lane = threadIdx.x & 63;
  const int wv = threadIdx.x >> 6;
  const size_t r0 = ((size_t)blockIdx.x * 4 + wv) * 16;
  const int col = lane & 15;
  const int kg = lane >> 4;

  const short* Qp = Q + (r0 + col) * EDIM + kg * 8;
  const short* Kp = KV + (r0 + col) * EDIM + kg * 8;
  f32x4 s = {};
  float wp = 0.f;
#pragma unroll
  for (int ks = 0; ks < 16; ++ks) {
    short8 a = *(const short8*)(Qp + ks * 32);
    short8 b = *(const short8*)(Kp + ks * 32);
    const f32x4 t0 = *(const f32x4*)(tvec + ks * 32 + kg * 8);
    const f32x4 t1 = *(const f32x4*)(tvec + ks * 32 + kg * 8 + 4);
#pragma unroll
    for (int i = 0; i < 4; ++i)
      wp += bf2f(b[i]) * t0[i] + bf2f(b[i + 4]) * t1[i];
    s = __builtin_amdgcn_mfma_f32_16x16x32_bf16(a, b, s, 0, 0, 0);
  }
  wp += __shfl_xor(wp, 16);
  wp += __shfl_xor(wp, 32);

  const float scale = 0.04419417382415922f;  // 1/sqrt(512)
  float p[4];
#pragma unroll
  for (int j = 0; j < 4; ++j) p[j] = (s[j] + wp) * scale;
#pragma unroll
  for (int j = 0; j < 4; ++j) {
    float m = p[j];
#pragma unroll
    for (int d = 1; d < 16; d <<= 1) m = fmaxf(m, __shfl_xor(m, d));
    float e = __expf(p[j] - m);
    float ssum = e;
#pragma unroll
    for (int d = 1; d < 16; d <<= 1) ssum += __shfl_xor(ssum, d);
    p[j] = e / ssum;
  }
#pragma unroll
  for (int j = 0; j < 4; ++j) plds[wv][kg * 4 + j][col] = p[j];
  __syncthreads();

  const int e0 = lane * 8;
  short8 v8[16];
#pragma unroll
  for (int k = 0; k < 16; ++k) v8[k] = *(const short8*)(KV + (r0 + k) * EDIM + e0);
#pragma unroll
  for (int q = 0; q < 16; ++q) {
    float acc[8] = {0, 0, 0, 0, 0, 0, 0, 0};
#pragma unroll
    for (int k = 0; k < 16; ++k) {
      const float pv = plds[wv][q][k];
#pragma unroll
      for (int i = 0; i < 8; ++i) acc[i] += pv * bf2f(v8[k][i]);
    }
    short8 y;
#pragma unroll
    for (int i = 0; i < 8; ++i) y[i] = f2bf(acc[i]);
    *(short8*)(Y + (r0 + q) * EDIM + e0) = y;
  }
}

// ------- out GEMM (r7 structure, 4 blocks/CU): out_d = Y_d @ Wv^T + bv, fp32 out ---
__global__ __launch_bounds__(256, 4) void out_gemm(
    const short* __restrict__ TV, const short* __restrict__ Wvb,
    const float* __restrict__ bv,
    float* __restrict__ out1, float* __restrict__ out2, size_t McE, int mblocks) {
  __shared__ short Al[128 * 64];
  __shared__ short Bl[128 * 64];

  int mb, zn;
  {
    const int L = blockIdx.x;
    if ((mblocks & 7) == 0) {
      const int mpx = mblocks >> 3;
      const int xcd = L & 7;
      const int slot = L >> 3;
      mb = xcd * mpx + slot / 8;
      zn = slot % 8;
    } else { mb = L / 8; zn = L % 8; }
  }
  const int z = zn >> 2;   // dir
  const int nb = zn & 3;

  const short* __restrict__ A = TV + (size_t)(2 + z) * McE;  // Y1 : Y2
  float* __restrict__ O = z ? out2 : out1;

  const int m0 = mb * 128;
  const int n0 = nb * 128;
  const int tid = threadIdx.x;
  const int lane = tid & 63;
  const int wv = tid >> 6;
  const int wr = wv >> 1, wc = wv & 1;
  const int col = lane & 15;
  const int kg = lane >> 4;

  f32x4 acc[4][4] = {};

  for (int ks = 0; ks < EDIM / 64; ++ks) {
    const int k0 = ks * 64;
    __syncthreads();
#pragma unroll
    for (int j = 0; j < 4; ++j) {
      const int g = (j * 4 + wv) * 64 + lane;
      const int row = g >> 3;
      const int sc = (g & 7) ^ (row & 7);
      gload_lds16(A + (size_t)(m0 + row) * EDIM + k0 + sc * 8, Al + (j * 4 + wv) * 512);
      gload_lds16(Wvb + (size_t)(n0 + row) * EDIM + k0 + sc * 8, Bl + (j * 4 + wv) * 512);
    }
    __syncthreads();
#pragma unroll
    for (int kk = 0; kk < 2; ++kk) {
      short8 af[4], bf8[4];
#pragma unroll
      for (int i = 0; i < 4; ++i) {
        const int ra = wr * 64 + i * 16 + col;
        const int rb = wc * 64 + i * 16 + col;
        af[i]  = *(const short8*)(Al + ra * 64 + ((((kk << 2) + kg) ^ (ra & 7)) << 3));
        bf8[i] = *(const short8*)(Bl + rb * 64 + ((((kk << 2) + kg) ^ (rb & 7)) << 3));
      }
#pragma unroll
      for (int mi = 0; mi < 4; ++mi)
#pragma unroll
        for (int nj = 0; nj < 4; ++nj)
          acc[mi][nj] = __builtin_amdgcn_mfma_f32_16x16x32_bf16(af[mi], bf8[nj], acc[mi][nj], 0, 0, 0);
    }
  }

#pragma unroll
  for (int mi = 0; mi < 4; ++mi) {
#pragma unroll
    for (int j = 0; j < 4; ++j) {
      const size_t r = m0 + wr * 64 + mi * 16 + kg * 4 + j;
#pragma unroll
      for (int nj = 0; nj < 4; ++nj) {
        const int e = n0 + wc * 64 + nj * 16 + col;
        O[r * EDIM + e] = acc[mi][nj][j] + bv[e];
      }
    }
  }
}

// ---------------- host ----------------
extern "C" void kernel_launch(void* const* d_in, const int* in_sizes, int n_in,
                              void* d_out, int out_size, void* d_ws, size_t ws_size,
                              hipStream_t stream) {
  const float* state1 = (const float*)d_in[0];
  const float* state2 = (const float*)d_in[1];
  const float* Wq = (const float*)d_in[2];
  const float* bq = (const float*)d_in[3];
  const float* Wk = (const float*)d_in[4];
  // d_in[5] = bk: softmax-invariant -> unused
  const float* Wv = (const float*)d_in[6];
  const float* bv = (const float*)d_in[7];

  const size_t Mtot = (size_t)8 * 4096;
  float* out1 = (float*)d_out;
  float* out2 = out1 + Mtot * EDIM;

  // ws layout: Wvb | Hb | tvec | per-chunk {S1b, S2b, T1,T2,Y1,Y2}
  short* Wvb = (short*)d_ws;
  short* Hb = Wvb + WELEMS;
  float* tvec = (float*)(Hb + WELEMS);
  short* base = (short*)(tvec + EDIM);

  const size_t fixed_bytes = (size_t)(2 * WELEMS) * 2 + EDIM * 4;
  size_t nch = 1;
  while (nch < 256) {
    size_t need = fixed_bytes + (size_t)6 * (Mtot / nch) * EDIM * 2;
    if (need <= ws_size) break;
    nch <<= 1;
  }
  const size_t Mc = Mtot / nch;
  const size_t McE = Mc * EDIM;
  const int mblocks = (int)(Mc / 128);
  short* S1b = base;
  short* S2b = S1b + McE;
  short* TV = S2b + McE;  // T1, T2, Y1, Y2

  for (size_t c = 0; c < nch; ++c) {
    const size_t roff = c * Mc;
    const int pb = (c == 0) ? 520 : 0;  // prep only on first chunk
    prep_convert<<<dim3((unsigned)(Mc / 4 + pb)), dim3(256), 0, stream>>>(
        state1 + roff * EDIM, state2 + roff * EDIM, Wq, bq, Wk, Wv,
        Wvb, tvec, Hb, S1b, S2b, pb);
    proj_t<<<dim3((unsigned)(mblocks * 8)), dim3(256), 0, stream>>>(
        S1b, S2b, Hb, TV, McE, mblocks);
    attn_y<<<dim3((unsigned)(Mc / 64), 2), dim3(256), 0, stream>>>(
        TV, S1b, S2b, tvec, McE);
    out_gemm<<<dim3((unsigned)(mblocks * 8)), dim3(256), 0, stream>>>(
        TV, Wvb, bv, out1 + roff * EDIM, out2 + roff * EDIM, McE, mblocks);
  }
}

// Round 14
// 169.091 us; speedup vs baseline: 2.0261x; 1.0970x over previous
//
#include <hip/hip_runtime.h>
#include <hip/hip_bf16.h>

typedef __attribute__((ext_vector_type(4))) float f32x4;
typedef __attribute__((ext_vector_type(8))) short short8;
typedef __attribute__((ext_vector_type(4))) short short4v;

#define EDIM 512
#define WELEMS 262144  // 512*512

static __device__ __forceinline__ short f2bf(float f) {
  union { float f; unsigned u; } v; v.f = f;
  unsigned r = v.u + 0x7fffu + ((v.u >> 16) & 1u);  // RNE
  return (short)(r >> 16);
}
static __device__ __forceinline__ float bf2f(short s) {
  union { float f; unsigned u; } v; v.u = ((unsigned)(unsigned short)s) << 16;
  return v.f;
}

// async global -> LDS, 16B per lane; lds base wave-uniform + lane*16 linear.
static __device__ __forceinline__ void gload_lds16(const short* g, short* l) {
  __builtin_amdgcn_global_load_lds(
      (const __attribute__((address_space(1))) unsigned int*)g,
      (__attribute__((address_space(3))) unsigned int*)(unsigned int)(unsigned long long)l,
      16, 0, 0);
}

// ---- merged prep + state convert, one dispatch ----
// blocks [0,256): Wv->bf16 | [256,264): tvec = Wk^T bq | [264,520): H = Wk^T Wq
// blocks [prep_blocks, ...): states fp32->bf16 (pure streaming, NT loads: the
// fp32 source is dead after this read -- keep L2 for the bf16 working set)
__global__ __launch_bounds__(256) void prep_convert(
    const float* __restrict__ s1, const float* __restrict__ s2,
    const float* __restrict__ Wq, const float* __restrict__ bq,
    const float* __restrict__ Wk, const float* __restrict__ Wv,
    short* __restrict__ Wvb, float* __restrict__ tvec, short* __restrict__ Hb,
    short* __restrict__ o1, short* __restrict__ o2, int prep_blocks) {
  __shared__ float sh[2][64][33];
  const int b = blockIdx.x;
  const int tid = threadIdx.x;
  if (b < prep_blocks) {
    if (b < 256) {
      int i = (b * 256 + tid) * 4;
      f32x4 v = *(const f32x4*)(Wv + i);
      short4v vs;
#pragma unroll
      for (int j = 0; j < 4; ++j) vs[j] = f2bf(v[j]);
      *(short4v*)(Wvb + i) = vs;
    } else if (b < 264) {
      float* red = &sh[0][0][0];  // [4][64]
      const int fl = tid & 63;
      const int part = tid >> 6;
      const int f = (b - 256) * 64 + fl;
      float s = 0.f;
      const int n0 = part * 128;
#pragma unroll 8
      for (int n = n0; n < n0 + 128; ++n) s += Wk[(size_t)n * EDIM + f] * bq[n];
      red[part * 64 + fl] = s;
      __syncthreads();
      if (part == 0)
        tvec[f] = ((red[fl] + red[64 + fl]) + (red[128 + fl] + red[192 + fl]));
    } else {
      const int hb = b - 264;
      const int bf = (hb >> 4) * 32;
      const int be = (hb & 15) * 32;
      const int fh = (tid & 15) * 2;
      const int eh = (tid >> 4) * 2;
      float a00 = 0, a01 = 0, a10 = 0, a11 = 0;
      for (int nc = 0; nc < 8; ++nc) {
        __syncthreads();
#pragma unroll
        for (int p = 0; p < 8; ++p) {
          const int idx = p * 256 + tid;  // 2048 = 64n x 32f
          const int n = idx >> 5, f = idx & 31;
          sh[0][n][f] = Wk[(size_t)(nc * 64 + n) * EDIM + bf + f];
          sh[1][n][f] = Wq[(size_t)(nc * 64 + n) * EDIM + be + f];
        }
        __syncthreads();
#pragma unroll 4
        for (int n = 0; n < 64; ++n) {
          const float k0 = sh[0][n][fh], k1 = sh[0][n][fh + 1];
          const float q0 = sh[1][n][eh], q1 = sh[1][n][eh + 1];
          a00 += k0 * q0; a01 += k0 * q1; a10 += k1 * q0; a11 += k1 * q1;
        }
      }
      Hb[(size_t)(bf + fh) * EDIM + be + eh] = f2bf(a00);
      Hb[(size_t)(bf + fh) * EDIM + be + eh + 1] = f2bf(a01);
      Hb[(size_t)(bf + fh + 1) * EDIM + be + eh] = f2bf(a10);
      Hb[(size_t)(bf + fh + 1) * EDIM + be + eh + 1] = f2bf(a11);
    }
  } else {
    const int cb = b - prep_blocks;
    const int wv = tid >> 6, lane = tid & 63;
    const size_t r = (size_t)cb * 4 + wv;
    const int off = lane * 8;
#pragma unroll
    for (int st = 0; st < 2; ++st) {
      const float* src = st ? s2 : s1;
      f32x4 a0 = __builtin_nontemporal_load((const f32x4*)(src + r * EDIM + off));
      f32x4 a1 = __builtin_nontemporal_load((const f32x4*)(src + r * EDIM + off + 4));
      short8 rb;
#pragma unroll
      for (int j = 0; j < 4; ++j) { rb[j] = f2bf(a0[j]); rb[j + 4] = f2bf(a1[j]); }
      *(short8*)((st ? o2 : o1) + r * EDIM + off) = rb;
    }
  }
}

// ------- T GEMM (r7 structure, 3 blocks/CU): T_d = X_d @ H^T, bf16 out -------
// grid = mblocks*8: zn = 8 combos (2 dirs x 4 nb), XCD decode.
// NOTE: (256,3) is the proven sweet spot; (256,5) spills MFMA acc (r12, 3x slower),
// (256,4) is neutral (r13).
__global__ __launch_bounds__(256, 3) void proj_t(
    const short* __restrict__ S1b, const short* __restrict__ S2b,
    const short* __restrict__ Hb,
    short* __restrict__ TV, size_t McE, int mblocks) {
  __shared__ short Al[128 * 64];
  __shared__ short Bl[128 * 64];

  int mb, zn;
  {
    const int L = blockIdx.x;
    if ((mblocks & 7) == 0) {
      const int mpx = mblocks >> 3;
      const int xcd = L & 7;
      const int slot = L >> 3;
      mb = xcd * mpx + slot / 8;
      zn = slot % 8;
    } else { mb = L / 8; zn = L % 8; }
  }
  const int z = zn >> 2;   // dir
  const int nb = zn & 3;

  const short* __restrict__ X = z ? S2b : S1b;
  short* __restrict__ O = TV + (size_t)z * McE;

  const int m0 = mb * 128;
  const int n0 = nb * 128;
  const int tid = threadIdx.x;
  const int lane = tid & 63;
  const int wv = tid >> 6;
  const int wr = wv >> 1, wc = wv & 1;
  const int col = lane & 15;
  const int kg = lane >> 4;

  f32x4 acc[4][4] = {};

  for (int ks = 0; ks < EDIM / 64; ++ks) {
    const int k0 = ks * 64;
    __syncthreads();
#pragma unroll
    for (int j = 0; j < 4; ++j) {
      const int g = (j * 4 + wv) * 64 + lane;
      const int row = g >> 3;
      const int sc = (g & 7) ^ (row & 7);
      gload_lds16(X + (size_t)(m0 + row) * EDIM + k0 + sc * 8, Al + (j * 4 + wv) * 512);
      gload_lds16(Hb + (size_t)(n0 + row) * EDIM + k0 + sc * 8, Bl + (j * 4 + wv) * 512);
    }
    __syncthreads();
#pragma unroll
    for (int kk = 0; kk < 2; ++kk) {
      short8 af[4], bf8[4];
#pragma unroll
      for (int i = 0; i < 4; ++i) {
        const int ra = wr * 64 + i * 16 + col;
        const int rb = wc * 64 + i * 16 + col;
        af[i]  = *(const short8*)(Al + ra * 64 + ((((kk << 2) + kg) ^ (ra & 7)) << 3));
        bf8[i] = *(const short8*)(Bl + rb * 64 + ((((kk << 2) + kg) ^ (rb & 7)) << 3));
      }
#pragma unroll
      for (int mi = 0; mi < 4; ++mi)
#pragma unroll
        for (int nj = 0; nj < 4; ++nj)
          acc[mi][nj] = __builtin_amdgcn_mfma_f32_16x16x32_bf16(af[mi], bf8[nj], acc[mi][nj], 0, 0, 0);
    }
  }

#pragma unroll
  for (int mi = 0; mi < 4; ++mi) {
#pragma unroll
    for (int j = 0; j < 4; ++j) {
      const size_t r = m0 + wr * 64 + mi * 16 + kg * 4 + j;
#pragma unroll
      for (int nj = 0; nj < 4; ++nj) {
        const int e = n0 + wc * 64 + nj * 16 + col;
        O[r * EDIM + e] = f2bf(acc[mi][nj][j]);
      }
    }
  }
}

// ------- block attention -> Y = P @ X (bf16) -------
// S = T@X^T + w[k], w[k] = X[k]·tvec computed in-loop from the K fragments;
// kg-reduce via shfl_xor(16|32). V eliminated (out = (P@X)@Wv^T + bv).
__global__ __launch_bounds__(256) void attn_y(
    const short* __restrict__ TV, const short* __restrict__ S1b, const short* __restrict__ S2b,
    const float* __restrict__ tvec, size_t McE) {
  __shared__ float plds[4][16][16];
  const int dir = blockIdx.y;
  const short* __restrict__ Q = TV + (size_t)dir * McE;     // T1 : T2
  const short* __restrict__ KV = dir ? S1b : S2b;
  short* __restrict__ Y = (short*)TV + (size_t)(2 + dir) * McE;

  const int lane = threadIdx.x & 63;
  const int wv = threadIdx.x >> 6;
  const size_t r0 = ((size_t)blockIdx.x * 4 + wv) * 16;
  const int col = lane & 15;
  const int kg = lane >> 4;

  const short* Qp = Q + (r0 + col) * EDIM + kg * 8;
  const short* Kp = KV + (r0 + col) * EDIM + kg * 8;
  f32x4 s = {};
  float wp = 0.f;
#pragma unroll
  for (int ks = 0; ks < 16; ++ks) {
    short8 a = *(const short8*)(Qp + ks * 32);
    short8 b = *(const short8*)(Kp + ks * 32);
    const f32x4 t0 = *(const f32x4*)(tvec + ks * 32 + kg * 8);
    const f32x4 t1 = *(const f32x4*)(tvec + ks * 32 + kg * 8 + 4);
#pragma unroll
    for (int i = 0; i < 4; ++i)
      wp += bf2f(b[i]) * t0[i] + bf2f(b[i + 4]) * t1[i];
    s = __builtin_amdgcn_mfma_f32_16x16x32_bf16(a, b, s, 0, 0, 0);
  }
  wp += __shfl_xor(wp, 16);
  wp += __shfl_xor(wp, 32);

  const float scale = 0.04419417382415922f;  // 1/sqrt(512)
  float p[4];
#pragma unroll
  for (int j = 0; j < 4; ++j) p[j] = (s[j] + wp) * scale;
#pragma unroll
  for (int j = 0; j < 4; ++j) {
    float m = p[j];
#pragma unroll
    for (int d = 1; d < 16; d <<= 1) m = fmaxf(m, __shfl_xor(m, d));
    float e = __expf(p[j] - m);
    float ssum = e;
#pragma unroll
    for (int d = 1; d < 16; d <<= 1) ssum += __shfl_xor(ssum, d);
    p[j] = e / ssum;
  }
#pragma unroll
  for (int j = 0; j < 4; ++j) plds[wv][kg * 4 + j][col] = p[j];
  __syncthreads();

  const int e0 = lane * 8;
  short8 v8[16];
#pragma unroll
  for (int k = 0; k < 16; ++k) v8[k] = *(const short8*)(KV + (r0 + k) * EDIM + e0);
#pragma unroll
  for (int q = 0; q < 16; ++q) {
    float acc[8] = {0, 0, 0, 0, 0, 0, 0, 0};
#pragma unroll
    for (int k = 0; k < 16; ++k) {
      const float pv = plds[wv][q][k];
#pragma unroll
      for (int i = 0; i < 8; ++i) acc[i] += pv * bf2f(v8[k][i]);
    }
    short8 y;
#pragma unroll
    for (int i = 0; i < 8; ++i) y[i] = f2bf(acc[i]);
    *(short8*)(Y + (r0 + q) * EDIM + e0) = y;
  }
}

// ------- out GEMM (r7 structure, 3 blocks/CU): out_d = Y_d @ Wv^T + bv, fp32 out ---
// NT stores: the 134 MB fp32 output is never re-read -- don't thrash L2.
__global__ __launch_bounds__(256, 3) void out_gemm(
    const short* __restrict__ TV, const short* __restrict__ Wvb,
    const float* __restrict__ bv,
    float* __restrict__ out1, float* __restrict__ out2, size_t McE, int mblocks) {
  __shared__ short Al[128 * 64];
  __shared__ short Bl[128 * 64];

  int mb, zn;
  {
    const int L = blockIdx.x;
    if ((mblocks & 7) == 0) {
      const int mpx = mblocks >> 3;
      const int xcd = L & 7;
      const int slot = L >> 3;
      mb = xcd * mpx + slot / 8;
      zn = slot % 8;
    } else { mb = L / 8; zn = L % 8; }
  }
  const int z = zn >> 2;   // dir
  const int nb = zn & 3;

  const short* __restrict__ A = TV + (size_t)(2 + z) * McE;  // Y1 : Y2
  float* __restrict__ O = z ? out2 : out1;

  const int m0 = mb * 128;
  const int n0 = nb * 128;
  const int tid = threadIdx.x;
  const int lane = tid & 63;
  const int wv = tid >> 6;
  const int wr = wv >> 1, wc = wv & 1;
  const int col = lane & 15;
  const int kg = lane >> 4;

  f32x4 acc[4][4] = {};

  for (int ks = 0; ks < EDIM / 64; ++ks) {
    const int k0 = ks * 64;
    __syncthreads();
#pragma unroll
    for (int j = 0; j < 4; ++j) {
      const int g = (j * 4 + wv) * 64 + lane;
      const int row = g >> 3;
      const int sc = (g & 7) ^ (row & 7);
      gload_lds16(A + (size_t)(m0 + row) * EDIM + k0 + sc * 8, Al + (j * 4 + wv) * 512);
      gload_lds16(Wvb + (size_t)(n0 + row) * EDIM + k0 + sc * 8, Bl + (j * 4 + wv) * 512);
    }
    __syncthreads();
#pragma unroll
    for (int kk = 0; kk < 2; ++kk) {
      short8 af[4], bf8[4];
#pragma unroll
      for (int i = 0; i < 4; ++i) {
        const int ra = wr * 64 + i * 16 + col;
        const int rb = wc * 64 + i * 16 + col;
        af[i]  = *(const short8*)(Al + ra * 64 + ((((kk << 2) + kg) ^ (ra & 7)) << 3));
        bf8[i] = *(const short8*)(Bl + rb * 64 + ((((kk << 2) + kg) ^ (rb & 7)) << 3));
      }
#pragma unroll
      for (int mi = 0; mi < 4; ++mi)
#pragma unroll
        for (int nj = 0; nj < 4; ++nj)
          acc[mi][nj] = __builtin_amdgcn_mfma_f32_16x16x32_bf16(af[mi], bf8[nj], acc[mi][nj], 0, 0, 0);
    }
  }

#pragma unroll
  for (int mi = 0; mi < 4; ++mi) {
#pragma unroll
    for (int j = 0; j < 4; ++j) {
      const size_t r = m0 + wr * 64 + mi * 16 + kg * 4 + j;
#pragma unroll
      for (int nj = 0; nj < 4; ++nj) {
        const int e = n0 + wc * 64 + nj * 16 + col;
        __builtin_nontemporal_store(acc[mi][nj][j] + bv[e], &O[r * EDIM + e]);
      }
    }
  }
}

// ---------------- host ----------------
extern "C" void kernel_launch(void* const* d_in, const int* in_sizes, int n_in,
                              void* d_out, int out_size, void* d_ws, size_t ws_size,
                              hipStream_t stream) {
  const float* state1 = (const float*)d_in[0];
  const float* state2 = (const float*)d_in[1];
  const float* Wq = (const float*)d_in[2];
  const float* bq = (const float*)d_in[3];
  const float* Wk = (const float*)d_in[4];
  // d_in[5] = bk: softmax-invariant -> unused
  const float* Wv = (const float*)d_in[6];
  const float* bv = (const float*)d_in[7];

  const size_t Mtot = (size_t)8 * 4096;
  float* out1 = (float*)d_out;
  float* out2 = out1 + Mtot * EDIM;

  // ws layout: Wvb | Hb | tvec | per-chunk {S1b, S2b, T1,T2,Y1,Y2}
  short* Wvb = (short*)d_ws;
  short* Hb = Wvb + WELEMS;
  float* tvec = (float*)(Hb + WELEMS);
  short* base = (short*)(tvec + EDIM);

  const size_t fixed_bytes = (size_t)(2 * WELEMS) * 2 + EDIM * 4;
  size_t nch = 1;
  while (nch < 256) {
    size_t need = fixed_bytes + (size_t)6 * (Mtot / nch) * EDIM * 2;
    if (need <= ws_size) break;
    nch <<= 1;
  }
  const size_t Mc = Mtot / nch;
  const size_t McE = Mc * EDIM;
  const int mblocks = (int)(Mc / 128);
  short* S1b = base;
  short* S2b = S1b + McE;
  short* TV = S2b + McE;  // T1, T2, Y1, Y2

  for (size_t c = 0; c < nch; ++c) {
    const size_t roff = c * Mc;
    const int pb = (c == 0) ? 520 : 0;  // prep only on first chunk
    prep_convert<<<dim3((unsigned)(Mc / 4 + pb)), dim3(256), 0, stream>>>(
        state1 + roff * EDIM, state2 + roff * EDIM, Wq, bq, Wk, Wv,
        Wvb, tvec, Hb, S1b, S2b, pb);
    proj_t<<<dim3((unsigned)(mblocks * 8)), dim3(256), 0, stream>>>(
        S1b, S2b, Hb, TV, McE, mblocks);
    attn_y<<<dim3((unsigned)(Mc / 64), 2), dim3(256), 0, stream>>>(
        TV, S1b, S2b, tvec, McE);
    out_gemm<<<dim3((unsigned)(mblocks * 8)), dim3(256), 0, stream>>>(
        TV, Wvb, bv, out1 + roff * EDIM, out2 + roff * EDIM, McE, mblocks);
  }
}